// Round 1
// 303.466 us; speedup vs baseline: 1.2525x; 1.2525x over previous
//
#include <hip/hip_runtime.h>
#include <hip/hip_bf16.h>

#define DD 64
#define NBLK 128          // partition pass blocks (each owns a contiguous edge chunk)
#define MAXBUK 1024       // max buckets => supports n <= 131072 (problem: n = 100000)
#define BSHIFT 7          // 128 nodes per bucket

typedef __attribute__((ext_vector_type(8))) short short8v;  // 8 bf16 MFMA A/B frag
typedef __attribute__((ext_vector_type(4))) float f32x4;    // MFMA C/D frag

__device__ __forceinline__ unsigned pk_bf16(float a, float b) {
    __hip_bfloat162 h = __float22bfloat162_rn(make_float2(a, b));
    unsigned u; __builtin_memcpy(&u, &h, 4); return u;
}
__device__ __forceinline__ short f2bf_s(float f) {   // RNE scalar (startup only)
    union { float f; unsigned u; } x; x.f = f;
    unsigned r = x.u + 0x7fff + ((x.u >> 16) & 1);
    return (short)(r >> 16);
}
__device__ __forceinline__ float bf_lo(unsigned u) { return __int_as_float(u << 16); }
__device__ __forceinline__ float bf_hi(unsigned u) { return __int_as_float(u & 0xffff0000u); }
__device__ __forceinline__ short8v u4_to_s8(uint4 u) {
    union { uint4 u; short8v s; } x; x.u = u; return x.s;
}

// =====================================================================
// CSR build via bucketed counting sort — ZERO global atomics.
// (replaces hist/fill: 2M device-scope random atomics @25G/s = 79us+
//  were the measured op-rate ceiling; LDS atomics are ~free)
// =====================================================================

// ---- pass 1: per-(bucket, block) counts of dst and src streams ----
__global__ __launch_bounds__(256) void part_count(
        const int* __restrict__ src, const int* __restrict__ dst,
        int* __restrict__ cnt, int E, int nbuk, int ce) {
    __shared__ int hd[MAXBUK], hs[MAXBUK];
    for (int i = threadIdx.x; i < MAXBUK; i += 256) { hd[i] = 0; hs[i] = 0; }
    __syncthreads();
    int e0 = blockIdx.x * ce;
    int e1 = min(e0 + ce, E);
    for (int e = e0 + (int)threadIdx.x; e < e1; e += 256) {
        atomicAdd(&hd[dst[e] >> BSHIFT], 1);
        atomicAdd(&hs[src[e] >> BSHIFT], 1);
    }
    __syncthreads();
    int L2 = nbuk * NBLK;
    // layout [bucket][block] so a FLAT exclusive scan yields global offsets
    for (int b = threadIdx.x; b < nbuk; b += 256) {
        cnt[b * NBLK + blockIdx.x]      = hd[b];
        cnt[L2 + b * NBLK + blockIdx.x] = hs[b];
    }
}

// ---- generic 3-phase exclusive scan (L <= 256*1024) ----
__global__ void scan1p(int* __restrict__ a, int* __restrict__ bsums, int L) {
    __shared__ int tmp[256];
    int gid = blockIdx.x * 256 + threadIdx.x;
    int v = (gid < L) ? a[gid] : 0;
    tmp[threadIdx.x] = v;
    __syncthreads();
    for (int off = 1; off < 256; off <<= 1) {
        int t = (threadIdx.x >= off) ? tmp[threadIdx.x - off] : 0;
        __syncthreads();
        tmp[threadIdx.x] += t;
        __syncthreads();
    }
    if (gid < L) a[gid] = tmp[threadIdx.x] - v;
    if (threadIdx.x == 255) bsums[blockIdx.x] = tmp[255];
}
__global__ void scan2p(int* __restrict__ bsums, int nb) {
    __shared__ int tmp[1024];
    int v = (threadIdx.x < (unsigned)nb) ? bsums[threadIdx.x] : 0;
    tmp[threadIdx.x] = v;
    __syncthreads();
    for (int off = 1; off < 1024; off <<= 1) {
        int t = (threadIdx.x >= off) ? tmp[threadIdx.x - off] : 0;
        __syncthreads();
        tmp[threadIdx.x] += t;
        __syncthreads();
    }
    if (threadIdx.x < (unsigned)nb) bsums[threadIdx.x] = tmp[threadIdx.x] - v;
}
__global__ void scan3p(int* __restrict__ a, const int* __restrict__ bsums, int L) {
    int gid = blockIdx.x * 256 + threadIdx.x;
    if (gid < L) a[gid] += bsums[blockIdx.x];
}

// ---- pass 2: scatter edges into bucket-partitioned order (LDS cursors) ----
// dst payload: (node&127)<<17 | src   (24 bits, n<=131072)
// src payload: 1 byte local node id (only the histogram is needed)
__global__ __launch_bounds__(256) void part_scatter(
        const int* __restrict__ src, const int* __restrict__ dst,
        const int* __restrict__ ofs,
        unsigned int* __restrict__ partD, unsigned char* __restrict__ partS,
        int E, int nbuk, int ce) {
    __shared__ int cd[MAXBUK], cs[MAXBUK];
    int L2 = nbuk * NBLK;
    for (int b = threadIdx.x; b < nbuk; b += 256) {
        cd[b] = ofs[b * NBLK + blockIdx.x];
        cs[b] = ofs[L2 + b * NBLK + blockIdx.x] - E;   // src-region scan includes sum(cntD)=E
    }
    __syncthreads();
    int e0 = blockIdx.x * ce;
    int e1 = min(e0 + ce, E);
    for (int e = e0 + (int)threadIdx.x; e < e1; e += 256) {
        int s = src[e], d = dst[e];
        int pd = atomicAdd(&cd[d >> BSHIFT], 1);
        partD[pd] = ((unsigned)(d & 127) << 17) | (unsigned)s;
        int ps = atomicAdd(&cs[s >> BSHIFT], 1);
        partS[ps] = (unsigned char)(s & 127);
    }
}

// ---- pass 3a: per dst-bucket: node hist -> rowptr + inn, scatter esrc ----
__global__ __launch_bounds__(256) void bucket_csr(
        const unsigned int* __restrict__ partD, const int* __restrict__ ofs,
        int* __restrict__ rowptr, int* __restrict__ esrc,
        float* __restrict__ inn, int E, int nbuk, int n) {
    __shared__ int h[128], sc[128], cu[128];
    int b = blockIdx.x, tid = threadIdx.x;
    int e0 = ofs[b * NBLK];
    int e1 = (b + 1 < nbuk) ? ofs[(b + 1) * NBLK] : E;
    if (tid < 128) h[tid] = 0;
    __syncthreads();
    for (int e = e0 + tid; e < e1; e += 256)
        atomicAdd(&h[partD[e] >> 17], 1);
    __syncthreads();
    if (tid < 128) sc[tid] = h[tid];
    __syncthreads();
    for (int off = 1; off < 128; off <<= 1) {
        int t = (tid < 128 && tid >= off) ? sc[tid - off] : 0;
        __syncthreads();
        if (tid < 128) sc[tid] += t;
        __syncthreads();
    }
    int nodeBase = b << BSHIFT;
    if (tid < 128) {
        int excl = e0 + sc[tid] - h[tid];
        cu[tid] = excl;
        int v = nodeBase + tid;
        if (v < n) {
            rowptr[v] = excl;
            inn[v] = rsqrtf((float)max(h[tid], 1));
        }
    }
    if (b == 0 && tid == 0) rowptr[n] = E;
    __syncthreads();
    for (int e = e0 + tid; e < e1; e += 256) {
        unsigned v = partD[e];
        int p = atomicAdd(&cu[v >> 17], 1);
        esrc[p] = (int)(v & 0x1FFFFu);
    }
}

// ---- pass 3b: per src-bucket: out-degree hist -> outn, rs ----
__global__ __launch_bounds__(256) void bucket_deg(
        const unsigned char* __restrict__ partS, const int* __restrict__ ofs,
        float* __restrict__ outn, float* __restrict__ rs,
        int E, int nbuk, int n) {
    __shared__ int h[128];
    int b = blockIdx.x, tid = threadIdx.x;
    int L2 = nbuk * NBLK;
    int f0 = ofs[L2 + b * NBLK] - E;
    int f1 = (b + 1 < nbuk) ? ofs[L2 + (b + 1) * NBLK] - E : E;
    if (tid < 128) h[tid] = 0;
    __syncthreads();
    for (int e = f0 + tid; e < f1; e += 256)
        atomicAdd(&h[(int)partS[e]], 1);
    __syncthreads();
    if (tid < 128) {
        int v = (b << BSHIFT) + tid;
        if (v < n) {
            float d = (float)max(h[tid], 1);
            outn[v] = rsqrtf(d);
            rs[v]   = sqrtf(d);
        }
    }
}

// ---------------- pre-scale: hs(bf16) = feats * outn ----------------
__global__ void scale_kernel(const float* __restrict__ feats, const float* __restrict__ outn,
                             unsigned short* __restrict__ hs, int n) {
    int idx = blockIdx.x * blockDim.x + threadIdx.x;   // one uint4 (8 feats) per thread
    if (idx < n * 8) {
        int v = idx >> 3;
        float s = outn[v];
        const float4* fp = (const float4*)feats + (size_t)idx * 2;
        float4 f0 = fp[0], f1 = fp[1];
        uint4 o;
        o.x = pk_bf16(f0.x * s, f0.y * s); o.y = pk_bf16(f0.z * s, f0.w * s);
        o.z = pk_bf16(f1.x * s, f1.y * s); o.w = pk_bf16(f1.z * s, f1.w * s);
        ((uint4*)hs)[idx] = o;
    }
}

// ---------------- fused per-layer: bf16 CSR gather + MFMA + LN + relu + JK (+pred on last) --
// (unchanged from the 379.5us version; verified layouts)
__global__ __launch_bounds__(256) void gcn_kernel(
    const int* __restrict__ rowptr, const int* __restrict__ esrc,
    const float* __restrict__ inn, const float* __restrict__ rs,
    const float* __restrict__ outn,
    const unsigned short* __restrict__ hs_in,
    const float* __restrict__ Wc, const float* __restrict__ bc,
    const float* __restrict__ Wr, const float* __restrict__ br,
    const float* __restrict__ Wp, const float* __restrict__ pb,
    const float* __restrict__ g, const float* __restrict__ bb,
    unsigned short* __restrict__ hs_out, float* __restrict__ h_final,
    float* __restrict__ pred_out,
    int first, int last, int n)
{
    __shared__ __align__(16) short sWf[24 * 64 * 8];  // 24 A-frags (Wc|Wr|Wp) x 64 lanes x 8 bf16
    __shared__ __align__(16) short sXa[4][16 * 72];   // per-wave 16-node bf16 rows (72-short pad)
    __shared__ float sEps[4 * 64];                    // bias | ln_g | ln_b | pred_b

    int lane = threadIdx.x & 63;
    int wave = threadIdx.x >> 6;        // 0..3
    int q   = lane & 15;                // mfma: node id
    int gg  = lane >> 4;                // mfma: k/feat quad
    int q8  = lane & 7;                 // gather: 16B chunk (feats q8*8..+7)
    int o8  = lane >> 3;                // gather: node-in-half 0..7

    for (int idx = threadIdx.x; idx < 64; idx += blockDim.x) {
        sEps[idx]       = bc[idx] + br[idx];
        sEps[64 + idx]  = g[idx];
        sEps[128 + idx] = bb[idx];
        sEps[192 + idx] = pb[idx];
    }
    // A-frags: f = mat*8 + ft*2 + kc ; elem j = W[kc*32+gg*8+j][ft*16+q]
    for (int f = wave * 6; f < wave * 6 + 6; ++f) {
        int mat = f >> 3, ft = (f >> 1) & 3, kc = f & 1;
        const float* Ws = (mat == 0) ? Wc : (mat == 1) ? Wr : Wp;
        int feat = ft * 16 + q;
        int k0 = kc * 32 + gg * 8;
        short8v fr;
        #pragma unroll
        for (int j = 0; j < 8; ++j) fr[j] = f2bf_s(Ws[(k0 + j) * DD + feat]);
        *(short8v*)&sWf[(f * 64 + lane) * 8] = fr;
    }
    __syncthreads();

    short* xrow_w = &sXa[wave][0];
    const short8v* wf = (const short8v*)sWf;
    int wgid = blockIdx.x * 4 + wave;
    int nwav = gridDim.x * 4;
    int ngrp = (n + 15) >> 4;

    for (int grp = wgid; grp < ngrp; grp += nwav) {
        int vbase = grp << 4;
        int vo = vbase + q;
        int vsel = min(vo, n - 1);

        // self row B-frags (raw bf16), issued early to overlap gather
        const uint4* hrow = (const uint4*)(hs_in + (size_t)vsel * DD);
        uint4 bh0u = hrow[gg];
        uint4 bh1u = hrow[4 + gg];
        float rsv  = rs[vsel];
        float innv = inn[vsel];

        // rowptr for the 16 nodes; per-lane start/deg for both halves
        int rp = rowptr[min(vbase + min(lane, 16), n)];
        int stA = __shfl(rp, o8);     int dgA = __shfl(rp, o8 + 1) - stA;
        int stB = __shfl(rp, o8 + 8); int dgB = __shfl(rp, o8 + 9) - stB;

        #pragma unroll
        for (int hh = 0; hh < 2; ++hh) {
            int st = hh ? stB : stA;
            int dg = hh ? dgB : dgA;
            // wave-uniform max degree over this half's 8 nodes
            int mdg = dg;
            mdg = max(mdg, __shfl_xor(mdg, 8));
            mdg = max(mdg, __shfl_xor(mdg, 16));
            mdg = max(mdg, __shfl_xor(mdg, 32));

            float a[8];
            #pragma unroll
            for (int c = 0; c < 8; ++c) a[c] = 0.0f;

            int id0 = (0 < dg) ? esrc[st + 0] : 0;  float m0 = (0 < dg) ? 1.f : 0.f;
            int id1 = (1 < dg) ? esrc[st + 1] : 0;  float m1 = (1 < dg) ? 1.f : 0.f;
            int id2 = (2 < dg) ? esrc[st + 2] : 0;  float m2 = (2 < dg) ? 1.f : 0.f;
            int id3 = (3 < dg) ? esrc[st + 3] : 0;  float m3 = (3 < dg) ? 1.f : 0.f;

            for (int t = 0; t < mdg; t += 4) {
                // 4 independent 16B row-chunk loads (wave: 4 x 1KB coalesced)
                uint4 r0 = *(const uint4*)(hs_in + (size_t)id0 * DD + q8 * 8);
                uint4 r1 = *(const uint4*)(hs_in + (size_t)id1 * DD + q8 * 8);
                uint4 r2 = *(const uint4*)(hs_in + (size_t)id2 * DD + q8 * 8);
                uint4 r3 = *(const uint4*)(hs_in + (size_t)id3 * DD + q8 * 8);
                float c0 = m0, c1 = m1, c2 = m2, c3 = m3;
                // prefetch next 4 edge indices (overlap row loads)
                int t4 = t + 4;
                id0 = (t4 + 0 < dg) ? esrc[st + t4 + 0] : 0;  m0 = (t4 + 0 < dg) ? 1.f : 0.f;
                id1 = (t4 + 1 < dg) ? esrc[st + t4 + 1] : 0;  m1 = (t4 + 1 < dg) ? 1.f : 0.f;
                id2 = (t4 + 2 < dg) ? esrc[st + t4 + 2] : 0;  m2 = (t4 + 2 < dg) ? 1.f : 0.f;
                id3 = (t4 + 3 < dg) ? esrc[st + t4 + 3] : 0;  m3 = (t4 + 3 < dg) ? 1.f : 0.f;
                // accumulate
                a[0] = fmaf(bf_lo(r0.x), c0, a[0]); a[1] = fmaf(bf_hi(r0.x), c0, a[1]);
                a[2] = fmaf(bf_lo(r0.y), c0, a[2]); a[3] = fmaf(bf_hi(r0.y), c0, a[3]);
                a[4] = fmaf(bf_lo(r0.z), c0, a[4]); a[5] = fmaf(bf_hi(r0.z), c0, a[5]);
                a[6] = fmaf(bf_lo(r0.w), c0, a[6]); a[7] = fmaf(bf_hi(r0.w), c0, a[7]);
                a[0] = fmaf(bf_lo(r1.x), c1, a[0]); a[1] = fmaf(bf_hi(r1.x), c1, a[1]);
                a[2] = fmaf(bf_lo(r1.y), c1, a[2]); a[3] = fmaf(bf_hi(r1.y), c1, a[3]);
                a[4] = fmaf(bf_lo(r1.z), c1, a[4]); a[5] = fmaf(bf_hi(r1.z), c1, a[5]);
                a[6] = fmaf(bf_lo(r1.w), c1, a[6]); a[7] = fmaf(bf_hi(r1.w), c1, a[7]);
                a[0] = fmaf(bf_lo(r2.x), c2, a[0]); a[1] = fmaf(bf_hi(r2.x), c2, a[1]);
                a[2] = fmaf(bf_lo(r2.y), c2, a[2]); a[3] = fmaf(bf_hi(r2.y), c2, a[3]);
                a[4] = fmaf(bf_lo(r2.z), c2, a[4]); a[5] = fmaf(bf_hi(r2.z), c2, a[5]);
                a[6] = fmaf(bf_lo(r2.w), c2, a[6]); a[7] = fmaf(bf_hi(r2.w), c2, a[7]);
                a[0] = fmaf(bf_lo(r3.x), c3, a[0]); a[1] = fmaf(bf_hi(r3.x), c3, a[1]);
                a[2] = fmaf(bf_lo(r3.y), c3, a[2]); a[3] = fmaf(bf_hi(r3.y), c3, a[3]);
                a[4] = fmaf(bf_lo(r3.z), c3, a[4]); a[5] = fmaf(bf_hi(r3.z), c3, a[5]);
                a[6] = fmaf(bf_lo(r3.w), c3, a[6]); a[7] = fmaf(bf_hi(r3.w), c3, a[7]);
            }

            // lane holds its node-chunk's final raw sums; pack + one LDS write
            uint4 w4;
            w4.x = pk_bf16(a[0], a[1]); w4.y = pk_bf16(a[2], a[3]);
            w4.z = pk_bf16(a[4], a[5]); w4.w = pk_bf16(a[6], a[7]);
            *(uint4*)&xrow_w[(hh * 8 + o8) * 72 + q8 * 8] = w4;
        }

        // ---- B-frags + 16 MFMA (separate conv/res accumulators) ----
        const short* xr = &xrow_w[q * 72];
        short8v ba0 = *(const short8v*)&xr[gg * 8];
        short8v ba1 = *(const short8v*)&xr[32 + gg * 8];
        short8v sh0 = u4_to_s8(bh0u);
        short8v sh1 = u4_to_s8(bh1u);

        f32x4 accC[4], accR[4];
        #pragma unroll
        for (int ft = 0; ft < 4; ++ft) {
            f32x4 c = {0.f, 0.f, 0.f, 0.f};
            c = __builtin_amdgcn_mfma_f32_16x16x32_bf16(wf[(ft * 2 + 0) * 64 + lane], ba0, c, 0, 0, 0);
            c = __builtin_amdgcn_mfma_f32_16x16x32_bf16(wf[(ft * 2 + 1) * 64 + lane], ba1, c, 0, 0, 0);
            accC[ft] = c;
            f32x4 r = {0.f, 0.f, 0.f, 0.f};
            r = __builtin_amdgcn_mfma_f32_16x16x32_bf16(wf[(8 + ft * 2 + 0) * 64 + lane], sh0, r, 0, 0, 0);
            r = __builtin_amdgcn_mfma_f32_16x16x32_bf16(wf[(8 + ft * 2 + 1) * 64 + lane], sh1, r, 0, 0, 0);
            accR[ft] = r;
        }

        // ---- combine (inn*conv + rs*res + bias) + LayerNorm + relu ----
        f32x4 ac[4];
        #pragma unroll
        for (int ft = 0; ft < 4; ++ft) {
            float4 b4 = *(const float4*)&sEps[ft * 16 + gg * 4];
            ac[ft][0] = fmaf(innv, accC[ft][0], fmaf(rsv, accR[ft][0], b4.x));
            ac[ft][1] = fmaf(innv, accC[ft][1], fmaf(rsv, accR[ft][1], b4.y));
            ac[ft][2] = fmaf(innv, accC[ft][2], fmaf(rsv, accR[ft][2], b4.z));
            ac[ft][3] = fmaf(innv, accC[ft][3], fmaf(rsv, accR[ft][3], b4.w));
        }
        float s = 0.f;
        #pragma unroll
        for (int ft = 0; ft < 4; ++ft) s += ac[ft][0] + ac[ft][1] + ac[ft][2] + ac[ft][3];
        s += __shfl_xor(s, 16); s += __shfl_xor(s, 32);
        float mu = s * (1.0f / 64.0f);
        float vsum = 0.f;
        #pragma unroll
        for (int ft = 0; ft < 4; ++ft) {
            #pragma unroll
            for (int r = 0; r < 4; ++r) { float d = ac[ft][r] - mu; vsum += d * d; }
        }
        vsum += __shfl_xor(vsum, 16); vsum += __shfl_xor(vsum, 32);
        float rinv = rsqrtf(vsum * (1.0f / 64.0f) + 1e-5f);

        float4 yv[4];
        #pragma unroll
        for (int ft = 0; ft < 4; ++ft) {
            float4 g4 = *(const float4*)&sEps[64 + ft * 16 + gg * 4];
            float4 c4 = *(const float4*)&sEps[128 + ft * 16 + gg * 4];
            yv[ft].x = fmaxf((ac[ft][0] - mu) * rinv * g4.x + c4.x, 0.f);
            yv[ft].y = fmaxf((ac[ft][1] - mu) * rinv * g4.y + c4.y, 0.f);
            yv[ft].z = fmaxf((ac[ft][2] - mu) * rinv * g4.z + c4.z, 0.f);
            yv[ft].w = fmaxf((ac[ft][3] - mu) * rinv * g4.w + c4.w, 0.f);
        }

        if (!last) {
            if (vo < n) {
                float on = outn[vo];
                #pragma unroll
                for (int ft = 0; ft < 4; ++ft) {
                    size_t off = (size_t)vo * DD + ft * 16 + gg * 4;
                    uint2 p;
                    p.x = pk_bf16(yv[ft].x * on, yv[ft].y * on);
                    p.y = pk_bf16(yv[ft].z * on, yv[ft].w * on);
                    *(uint2*)&hs_out[off] = p;
                    if (first) {
                        *(float4*)&h_final[off] = yv[ft];
                    } else {
                        float4 hf = *(const float4*)&h_final[off];
                        hf.x += yv[ft].x; hf.y += yv[ft].y;
                        hf.z += yv[ft].z; hf.w += yv[ft].w;
                        *(float4*)&h_final[off] = hf;
                    }
                }
            }
        } else {
            // fused prediction: hf = h_final + y -> LDS (bf16) -> B-frags -> 8 MFMA -> d_out
            #pragma unroll
            for (int ft = 0; ft < 4; ++ft) {
                float4 hf = make_float4(0.f, 0.f, 0.f, 0.f);
                if (vo < n) {
                    float4 old = *(const float4*)&h_final[(size_t)vo * DD + ft * 16 + gg * 4];
                    hf.x = old.x + yv[ft].x; hf.y = old.y + yv[ft].y;
                    hf.z = old.z + yv[ft].z; hf.w = old.w + yv[ft].w;
                }
                uint2 p;
                p.x = pk_bf16(hf.x, hf.y);
                p.y = pk_bf16(hf.z, hf.w);
                *(uint2*)&xrow_w[q * 72 + ft * 16 + gg * 4] = p;   // same-wave DS, in order
            }
            short8v bp0 = *(const short8v*)&xr[gg * 8];
            short8v bp1 = *(const short8v*)&xr[32 + gg * 8];
            #pragma unroll
            for (int ft = 0; ft < 4; ++ft) {
                f32x4 p = {0.f, 0.f, 0.f, 0.f};
                p = __builtin_amdgcn_mfma_f32_16x16x32_bf16(wf[(16 + ft * 2 + 0) * 64 + lane], bp0, p, 0, 0, 0);
                p = __builtin_amdgcn_mfma_f32_16x16x32_bf16(wf[(16 + ft * 2 + 1) * 64 + lane], bp1, p, 0, 0, 0);
                if (vo < n) {
                    float4 b4 = *(const float4*)&sEps[192 + ft * 16 + gg * 4];
                    float4 o = make_float4(p[0] + b4.x, p[1] + b4.y, p[2] + b4.z, p[3] + b4.w);
                    *(float4*)&pred_out[(size_t)vo * DD + ft * 16 + gg * 4] = o;
                }
            }
        }
    }
}

extern "C" void kernel_launch(void* const* d_in, const int* in_sizes, int n_in,
                              void* d_out, int out_size, void* d_ws, size_t ws_size,
                              hipStream_t stream) {
    const float* feats  = (const float*)d_in[0];
    const int*   src    = (const int*)d_in[1];
    const int*   dst    = (const int*)d_in[2];
    const float* conv_W = (const float*)d_in[3];
    const float* conv_b = (const float*)d_in[4];
    const float* res_W  = (const float*)d_in[5];
    const float* res_b  = (const float*)d_in[6];
    const float* ln_g   = (const float*)d_in[7];
    const float* ln_b   = (const float*)d_in[8];
    const float* pred_W = (const float*)d_in[9];
    const float* pred_b = (const float*)d_in[10];

    int N = in_sizes[0] / DD;
    int E = in_sizes[1];

    int nbuk = (N + (1 << BSHIFT) - 1) >> BSHIFT;        // 782 for N=100000
    int ce   = (E + NBLK - 1) / NBLK;                    // edges per partition block
    int L    = nbuk * NBLK * 2;                          // flat count array length
    int nb   = (L + 255) / 256;                          // scan blocks (782 <= 1024)

    // workspace layout (~58 MB)
    int*   rowptr = (int*)d_ws;                          // N+1
    int*   cnt    = rowptr + (N + 1);                    // MAXBUK*NBLK*2 reserved (1 MB)
    int*   bsums  = cnt + MAXBUK * NBLK * 2;             // 1024
    int*   esrc   = bsums + 1024;                        // E
    float* outn   = (float*)(esrc + E);                  // N
    float* inn    = outn + N;                            // N
    float* rs     = inn + N;                             // N
    float* base   = (float*)(((uintptr_t)(rs + N) + 15) & ~(uintptr_t)15);
    unsigned short* hsA = (unsigned short*)base;                     // N*64 bf16
    unsigned short* hsB = (unsigned short*)(base + (size_t)N * 32);  // N*64 bf16
    float* hfin  = base + (size_t)N * 64;                // N*64 fp32
    // partition scratch aliases hfin (dead before layer-0 writes hfin)
    unsigned int*  partD = (unsigned int*)hfin;                      // E uints (4 MB)
    unsigned char* partS = (unsigned char*)(partD + E);              // E bytes (1 MB)

    part_count  <<<NBLK, 256, 0, stream>>>(src, dst, cnt, E, nbuk, ce);
    scan1p      <<<nb, 256, 0, stream>>>(cnt, bsums, L);
    scan2p      <<<1, 1024, 0, stream>>>(bsums, nb);
    scan3p      <<<nb, 256, 0, stream>>>(cnt, bsums, L);
    part_scatter<<<NBLK, 256, 0, stream>>>(src, dst, cnt, partD, partS, E, nbuk, ce);
    bucket_csr  <<<nbuk, 256, 0, stream>>>(partD, cnt, rowptr, esrc, inn, E, nbuk, N);
    bucket_deg  <<<nbuk, 256, 0, stream>>>(partS, cnt, outn, rs, E, nbuk, N);
    scale_kernel<<<(N * 8 + 255) / 256, 256, 0, stream>>>(feats, outn, hsA, N);

    // L1: hsA->hsB ; L2: hsB->hsA ; L3: hsA->(pred d_out), hs_out unused
    const unsigned short* ins[3]  = {hsA, hsB, hsA};
    unsigned short*       outs[3] = {hsB, hsA, hsB};
    for (int l = 0; l < 3; ++l) {
        gcn_kernel<<<1024, 256, 0, stream>>>(
            rowptr, esrc, inn, rs, outn, ins[l],
            conv_W + (size_t)l * DD * DD, conv_b + (size_t)l * DD,
            res_W  + (size_t)l * DD * DD, res_b  + (size_t)l * DD,
            pred_W, pred_b,
            ln_g   + (size_t)l * DD,      ln_b   + (size_t)l * DD,
            outs[l], hfin, (float*)d_out,
            (l == 0) ? 1 : 0, (l == 2) ? 1 : 0, N);
    }
}